// Round 4
// baseline (247.485 us; speedup 1.0000x reference)
//
#include <hip/hip_runtime.h>
#include <cmath>

// YOLOv8 loss, B=32, A=8400, G=40, C=80, R=16.
// R8 (= R7 + k_topk de-serialization):
//   k_pre  : DMA double-buffer (proven R5), softplus -> preacc slots; block 0
//            also zeroes acc+cnt (moved from k_topk).
//   k_topk : per-thread top-10 -> per-WAVE top-10 (10 butterfly rounds, NO
//            barriers) -> single __syncthreads -> wave-0 merge of 4x10 sorted
//            candidates -> lanes 0..9 publish winners in PARALLEL via
//            atomicMax(packed, iou_bits<<32 | 63-g). Replaces the 20-barrier
//            10-round block tournament with 1 barrier + parallel publish.
//   k_loss : reads packed (best iou + argmax-g directly), atomic slot
//            accumulation; LAST block (done-counter) reduces slots + preacc
//            and writes out[0].
// (R9 = R8 resubmitted verbatim: R3's bench died to a container-acquisition
// infra failure, not a kernel verdict; hang-audit found no deadlock path.)

namespace {

constexpr int B = 32;
constexpr int A = 8400;
constexpr int G = 40;
constexpr int C = 80;
constexpr float EPS = 1e-7f;
constexpr float IMG = 640.0f;

// k_pre tiling (proven R5)
constexpr int TPW = 16;                    // anchors per wave-tile
constexpr int NT = B * A / TPW;            // 16800 tiles (exact)
constexpr int PRE_BLOCKS = 512;
constexpr int NWAVES = PRE_BLOCKS * 4;     // 2048 waves
constexpr int DIST_B = TPW * 64;           // 4096 B dist per tile
constexpr int CLS_B = TPW * 320;           // 5120 B cls per tile
constexpr int SLICE = DIST_B + CLS_B;      // 9216 B per buffer

constexpr int NLB = B * A / 256;           // 1050 loss blocks

#define AS1 __attribute__((address_space(1)))
#define AS3 __attribute__((address_space(3)))

// Async global->LDS DMA, 16 B per lane. LDS dest = uniform base + lane*16.
__device__ __forceinline__ void gload_lds16(const void* g, void* l) {
  __builtin_amdgcn_global_load_lds((AS1 void*)(g), (AS3 void*)(l), 16, 0, 0);
}

__device__ __forceinline__ void anchor_of(int a, float& ax, float& ay, float& st) {
  int x, y;
  if (a < 6400)      { x = a % 80; y = a / 80; st = 8.0f; }
  else if (a < 8000) { int t = a - 6400; x = t % 40; y = t / 40; st = 16.0f; }
  else               { int t = a - 8000; x = t % 20; y = t / 20; st = 32.0f; }
  ax = ((float)x + 0.5f) * st;
  ay = ((float)y + 0.5f) * st;
}

// 20 cls logits (this lane's quarter of one anchor): max logit + softplus sum.
__device__ __forceinline__ void cls_part(const float4* c, float& sp, float& mx) {
  float relu = 0.f, p0 = 1.f, p1 = 1.f;
  mx = -3.4e38f;
#pragma unroll
  for (int q = 0; q < 5; ++q) {
    float xs[4] = {c[q].x, c[q].y, c[q].z, c[q].w};
#pragma unroll
    for (int e = 0; e < 4; ++e) {
      float x = xs[e];
      mx = fmaxf(mx, x);
      relu += fmaxf(x, 0.f);
      float ee = __expf(-fabsf(x));
      if (q < 3) p0 *= (1.f + ee); else p1 *= (1.f + ee);
    }
  }
  sp = relu + 0.69314718056f * (__log2f(p0) + __log2f(p1));
}

// softmax-expectation over 16 logits held in 4 float4s.
__device__ __forceinline__ float dist_expect(float4 w0, float4 w1, float4 w2, float4 w3) {
  float x[16] = {w0.x, w0.y, w0.z, w0.w, w1.x, w1.y, w1.z, w1.w,
                 w2.x, w2.y, w2.z, w2.w, w3.x, w3.y, w3.z, w3.w};
  float m = x[0];
#pragma unroll
  for (int e = 1; e < 16; ++e) m = fmaxf(m, x[e]);
  float se = 0.f, sj = 0.f;
#pragma unroll
  for (int e = 0; e < 16; ++e) {
    float ee = __expf(x[e] - m);
    se += ee;
    sj += ee * (float)e;
  }
  return sj / se;
}

// Stage one 16-anchor tile into this wave's LDS buffer (9 async DMA ops).
__device__ __forceinline__ void stage_tile(const char* dbase, const char* cbase,
                                           int tile, char* lbuf, int lane) {
  const char* gd = dbase + (size_t)tile * DIST_B + lane * 16;
  const char* gc = cbase + (size_t)tile * CLS_B + lane * 16;
#pragma unroll
  for (int r = 0; r < 4; ++r) gload_lds16(gd + r * 1024, lbuf + r * 1024);
#pragma unroll
  for (int q = 0; q < 5; ++q) gload_lds16(gc + q * 1024, lbuf + DIST_B + q * 1024);
}

// ---------------------------------------------------------------------------
// k_pre: wave-private DMA double-buffer over 16-anchor tiles.
// Outputs: pbox, msqrt, packed=0, preacc[block] softplus partial.
// Block 0 additionally zeroes acc[0..47] + cnt for k_loss (visible at the
// dispatch boundary; nothing else touches them before k_loss).
// ---------------------------------------------------------------------------
__global__ __launch_bounds__(256) void k_pre(
    const float* __restrict__ pred_dist, const float* __restrict__ pred_cls,
    float* __restrict__ pbox, float* __restrict__ msqrt,
    unsigned long long* __restrict__ packed, double* __restrict__ preacc,
    double* __restrict__ acc, unsigned int* __restrict__ cnt) {
  __shared__ char smem[4 * 2 * SLICE];   // 73728 B: 4 waves x 2 buffers x 9 KB
  __shared__ double shb[4];
  int t = threadIdx.x, lane = t & 63, wid = t >> 6;
  if (blockIdx.x == 0) {
    if (t < 48) acc[t] = 0.0;
    else if (t == 48) *cnt = 0u;
  }
  int j = lane & 3, a16 = lane >> 2;
  char* slice = smem + wid * (2 * SLICE);
  const char* dbase = (const char*)pred_dist;
  const char* cbase = (const char*)pred_cls;

  double spsum = 0.0;
  int cur = blockIdx.x * 4 + wid;
  int buf = 0;
  if (cur < NT) stage_tile(dbase, cbase, cur, slice, lane);

  while (cur < NT) {
    int nxt = cur + NWAVES;
    if (nxt < NT) {
      stage_tile(dbase, cbase, nxt, slice + (buf ^ 1) * SLICE, lane);
      // vmcnt(9): tile `cur`'s 9 DMAs (and older stores) retired; next tile's
      // 9 stay in flight. expcnt/lgkmcnt fields set to no-wait.
      __builtin_amdgcn_s_waitcnt(0xF79);
    } else {
      __builtin_amdgcn_s_waitcnt(0xF70);   // vmcnt(0)
    }

    const char* bp = slice + buf * SLICE;
    // ---- cls: quad layout identical to global layout ----
    float4 c[5];
    const float4* cl = (const float4*)(bp + DIST_B + a16 * 320 + j * 16);
#pragma unroll
    for (int q = 0; q < 5; ++q) c[q] = cl[q * 4];   // byte stride 64
    float sp, mx;
    cls_part(c, sp, mx);
    mx = fmaxf(mx, __shfl_xor(mx, 1));
    mx = fmaxf(mx, __shfl_xor(mx, 2));

    // ---- dist: lane j owns side j of its anchor ----
    const float4* dl = (const float4*)(bp + a16 * 256 + j * 64);
    float de = dist_expect(dl[0], dl[1], dl[2], dl[3]);
    int qb = lane & ~3;
    float e0 = __shfl(de, qb), e1 = __shfl(de, qb + 1);
    float e2 = __shfl(de, qb + 2), e3 = __shfl(de, qb + 3);

    int i = cur * TPW + a16;
    if (j == 0) {
      int a = i % A;
      float ax, ay, st;
      anchor_of(a, ax, ay, st);
      float4 ob;
      ob.x = fminf(fmaxf(ax - e0 * st, 0.f), IMG);
      ob.y = fminf(fmaxf(ay - e1 * st, 0.f), IMG);
      ob.z = fminf(fmaxf(ax + e2 * st, 0.f), IMG);
      ob.w = fminf(fmaxf(ay + e3 * st, 0.f), IMG);
      reinterpret_cast<float4*>(pbox)[i] = ob;
      msqrt[i] = sqrtf(1.f / (1.f + __expf(-mx)));
      packed[i] = 0ull;
    }
    spsum += (double)sp;
    cur = nxt;
    buf ^= 1;
  }

  // ---- block-reduce softplus sum -> private slot (no atomic, no memset) ----
#pragma unroll
  for (int off = 32; off; off >>= 1) spsum += __shfl_xor(spsum, off);
  if (lane == 0) shb[wid] = spsum;
  __syncthreads();
  if (t == 0) preacc[blockIdx.x] = shb[0] + shb[1] + shb[2] + shb[3];
}

// ---------------------------------------------------------------------------
// k_topk: one block per (b,g). Per-thread exact top-10 (insert cascade only
// fires for v>0) -> per-wave top-10 via 10 barrier-free butterfly rounds
// (lane k latches round-k winner) -> one __syncthreads -> wave 0 merges the
// 4x10 candidates (anchor indices globally unique -> index-match consume) ->
// lanes 0..9 publish in parallel: atomicMax(packed, iou<<32 | 63-g).
// Max = highest iou; ties -> smallest g (argmax-first semantics).
// ---------------------------------------------------------------------------
__global__ __launch_bounds__(256) void k_topk(
    const float* __restrict__ pbox, const float* __restrict__ msqrt,
    const float* __restrict__ gt_bboxes, unsigned long long* __restrict__ packed) {
  int bg = blockIdx.x;
  int t = threadIdx.x, lane = t & 63, wid = t >> 6;
  int b = bg / G, g = bg % G;
  const float* gp = gt_bboxes + (size_t)bg * 4;
  float gx1 = gp[0], gy1 = gp[1], gx2 = gp[2], gy2 = gp[3];
  float garea = (gx2 - gx1) * (gy2 - gy1);
  const float4* pb = reinterpret_cast<const float4*>(pbox) + (size_t)b * A;
  const float* ms = msqrt + (size_t)b * A;

  float lv[10];
  int li[10];
#pragma unroll
  for (int s = 0; s < 10; ++s) { lv[s] = 0.f; li[s] = 0x7fffffff; }

  for (int a = t; a < A; a += 256) {
    float4 p = pb[a];
    float iw = fmaxf(fminf(gx2, p.z) - fmaxf(gx1, p.x), 0.f);
    float ih = fmaxf(fminf(gy2, p.w) - fmaxf(gy1, p.y), 0.f);
    float inter = iw * ih;
    float parea = (p.z - p.x) * (p.w - p.y);
    float iou = inter / (garea + parea - inter + EPS);
    float i2 = iou * iou;
    float v = ms[a] * i2 * i2 * i2;     // cls^0.5 * iou^6
    if (v > lv[9] || (v == lv[9] && v > 0.f && a < li[9])) {
      float cv = v; int ci = a;
#pragma unroll
      for (int s = 0; s < 10; ++s) {
        bool bt = (cv > lv[s]) || (cv == lv[s] && ci < li[s]);
        float tv = bt ? cv : lv[s]; int ti = bt ? ci : li[s];
        cv = bt ? lv[s] : cv; ci = bt ? li[s] : ci;
        lv[s] = tv; li[s] = ti;
      }
    }
  }

  // ---- per-wave top-10: 10 butterfly-argmax rounds, no barriers ----
  __shared__ float lwv[40];
  __shared__ int lwi[40];
  float kv = 0.f; int ki = 0x7fffffff;   // lane k holds round-k winner
  int ptr = 0;
  for (int k = 0; k < 10; ++k) {
    float hv = lv[0]; int hi = li[0];
#pragma unroll
    for (int s = 1; s < 10; ++s) { bool sel = (ptr == s); hv = sel ? lv[s] : hv; hi = sel ? li[s] : hi; }
    if (ptr > 9) { hv = -1.f; hi = -1; }
    float rv = hv; int ri = hi;
#pragma unroll
    for (int off = 32; off; off >>= 1) {
      float ov = __shfl_xor(rv, off); int oi = __shfl_xor(ri, off);
      if (ov > rv || (ov == rv && oi < ri)) { rv = ov; ri = oi; }
    }
    if (rv <= 0.f) break;    // sorted: all remaining are invalid too
    if (lane == k) { kv = rv; ki = ri; }
    if (hi == ri) ptr++;     // unique anchor index -> exactly one lane advances
  }
  if (lane < 10) { lwv[wid * 10 + lane] = kv; lwi[wid * 10 + lane] = ki; }
  __syncthreads();

  // ---- wave-0 merge of 4 sorted 10-lists + parallel publish ----
  if (wid == 0) {
    float mv = 0.f; int mi = 0x7fffffff;
    if (lane < 40) { mv = lwv[lane]; mi = lwi[lane]; }
    int outi = -1;
    for (int k = 0; k < 10; ++k) {
      float rv = mv; int ri = mi;
#pragma unroll
      for (int off = 32; off; off >>= 1) {
        float ov = __shfl_xor(rv, off); int oi = __shfl_xor(ri, off);
        if (ov > rv || (ov == rv && oi < ri)) { rv = ov; ri = oi; }
      }
      if (rv <= 0.f) break;
      if (lane == k) outi = ri;          // lane k owns winner k
      if (mi == ri) { mv = 0.f; mi = 0x7fffffff; }  // consume (index unique)
    }
    if (outi >= 0) {
      // Winner valid (v>0 => iou>0). Recompute its iou (identical expression
      // as the scan -> identical value) and publish.
      float4 p = pb[outi];
      float iw = fmaxf(fminf(gx2, p.z) - fmaxf(gx1, p.x), 0.f);
      float ih = fmaxf(fminf(gy2, p.w) - fmaxf(gy1, p.y), 0.f);
      float inter = iw * ih;
      float parea = (p.z - p.x) * (p.w - p.y);
      float iou = inter / (garea + parea - inter + EPS);
      unsigned long long pk =
          ((unsigned long long)__float_as_uint(iou) << 32) | (unsigned int)(63 - g);
      atomicMax(&packed[(size_t)b * A + outi], pk);
    }
  }
}

__device__ __forceinline__ float ciou_f(float4 p, float t0, float t1, float t2, float t3) {
  float iw = fmaxf(fminf(p.z, t2) - fmaxf(p.x, t0), 0.f);
  float ih = fmaxf(fminf(p.w, t3) - fmaxf(p.y, t1), 0.f);
  float inter = iw * ih;
  float w1 = fmaxf(p.z - p.x, EPS), h1 = fmaxf(p.w - p.y, EPS);
  float w2 = fmaxf(t2 - t0, EPS), h2 = fmaxf(t3 - t1, EPS);
  float uni = w1 * h1 + w2 * h2 - inter + EPS;
  float iou = inter / uni;
  float cw = fmaxf(p.z, t2) - fminf(p.x, t0);
  float ch = fmaxf(p.w, t3) - fminf(p.y, t1);
  float c2 = cw * cw + ch * ch + EPS;
  float dx = (p.x + p.z) * 0.5f - (t0 + t2) * 0.5f;
  float dy = (p.y + p.w) * 0.5f - (t1 + t3) * 0.5f;
  float rho2 = dx * dx + dy * dy;
  float dat = atanf(w2 / h2) - atanf(w1 / h1);
  const float c4pi2 = (float)(4.0 / (M_PI * M_PI));
  float v = c4pi2 * dat * dat;
  float alpha = v / (1.0f - iou + v + EPS);
  float r = iou - (rho2 / c2 + v * alpha);
  return fminf(fmaxf(r, -1.f), 1.f);
}

__device__ __forceinline__ float wave_sum(float v) {
#pragma unroll
  for (int off = 32; off; off >>= 1) v += __shfl_xor(v, off);
  return v;
}

__device__ __forceinline__ double wave_sum_d(double v) {
#pragma unroll
  for (int off = 32; off; off >>= 1) v += __shfl_xor(v, off);
  return v;
}

// ---------------------------------------------------------------------------
// k_loss: packed-driven. acc slots: [0]=bce, [1]=score_sum, [2]=num_fg,
// [3]=box, [4]=dfl (x8 slots each). Grid = B*A/256. The LAST block to finish
// (done-counter) re-reads the atomic slots at the coherence point
// (atomicAdd(p, 0.0)) + preacc, and writes out[0].
// ---------------------------------------------------------------------------
__global__ __launch_bounds__(256) void k_loss(
    const float* __restrict__ pred_dist, const float* __restrict__ pred_cls,
    const int* __restrict__ gt_labels, const float* __restrict__ gt_bboxes,
    const float* __restrict__ pbox, const unsigned long long* __restrict__ packed,
    double* __restrict__ acc, const double* __restrict__ preacc,
    unsigned int* __restrict__ cnt, float* __restrict__ out) {
  int t = threadIdx.x, lane = t & 63, wid = t >> 6;
  int i = blockIdx.x * 256 + t;
  int b = i / A, a = i - b * A;
  unsigned long long pk = packed[i];
  float corr = 0.f, sc = 0.f, nfg = 0.f, box = 0.f, dfl = 0.f;
  if (pk) {
    int bestg = 63 - (int)(pk & 63ull);
    float best = __uint_as_float((unsigned int)(pk >> 32));
    float4 p = reinterpret_cast<const float4*>(pbox)[i];
    sc = best;
    nfg = 1.f;
    int lab = gt_labels[b * G + bestg];
    lab = lab < 0 ? 0 : (lab > C - 1 ? C - 1 : lab);
    float xl = pred_cls[(size_t)i * C + lab];
    corr = -xl * best;                 // the -x*t BCE term
    const float* gp = gt_bboxes + (size_t)(b * G + bestg) * 4;
    float t0 = gp[0], t1 = gp[1], t2 = gp[2], t3 = gp[3];
    box = 1.0f - ciou_f(p, t0, t1, t2, t3);
    float ax, ay, st;
    anchor_of(a, ax, ay, st);
    float rst = 1.f / st;
    float tgt[4] = {(ax - t0) * rst, (ay - t1) * rst, (t2 - ax) * rst, (t3 - ay) * rst};
    const float4* dr = reinterpret_cast<const float4*>(pred_dist) + (size_t)i * 16;
    const float* drf = pred_dist + (size_t)i * 64;
#pragma unroll
    for (int l = 0; l < 4; ++l) {
      float4 u0 = dr[4 * l], u1 = dr[4 * l + 1], u2 = dr[4 * l + 2], u3 = dr[4 * l + 3];
      float xs[16] = {u0.x, u0.y, u0.z, u0.w, u1.x, u1.y, u1.z, u1.w,
                      u2.x, u2.y, u2.z, u2.w, u3.x, u3.y, u3.z, u3.w};
      float m = xs[0];
#pragma unroll
      for (int e = 1; e < 16; ++e) m = fmaxf(m, xs[e]);
      float se = 0.f;
#pragma unroll
      for (int e = 0; e < 16; ++e) se += __expf(xs[e] - m);
      float lse = m + __logf(se);
      float tt = fminf(fmaxf(tgt[l], 0.f), 14.99f);
      int tl = (int)tt;                 // tt >= 0 so trunc == floor
      float wr = tt - (float)tl;
      float wl = 1.f - wr;
      float xa = drf[l * 16 + tl];      // L1-hot re-read, avoids scratch array
      float xb = drf[l * 16 + tl + 1];
      dfl += (lse - xa) * wl + (lse - xb) * wr;
    }
  }
  float s0 = wave_sum(corr), s1 = wave_sum(sc), s2 = wave_sum(nfg);
  float s3 = wave_sum(box), s4 = wave_sum(dfl);
  __shared__ float sh[4][5];
  __shared__ double sq[4];
  __shared__ double sacc[40];
  __shared__ int isLast;
  if (lane == 0) { sh[wid][0] = s0; sh[wid][1] = s1; sh[wid][2] = s2; sh[wid][3] = s3; sh[wid][4] = s4; }
  __syncthreads();
  if (t == 0) {
    double a0 = 0, a1 = 0, a2 = 0, a3 = 0, a4 = 0;
#pragma unroll
    for (int w = 0; w < 4; ++w) {
      a0 += sh[w][0]; a1 += sh[w][1]; a2 += sh[w][2]; a3 += sh[w][3]; a4 += sh[w][4];
    }
    if (a2 != 0.0) {
      int slot = blockIdx.x & 7;
      atomicAdd(&acc[0 * 8 + slot], a0);
      atomicAdd(&acc[1 * 8 + slot], a1);
      atomicAdd(&acc[2 * 8 + slot], a2);
      atomicAdd(&acc[3 * 8 + slot], a3);
      atomicAdd(&acc[4 * 8 + slot], a4);
    }
    __threadfence();                       // release our adds before the ticket
    unsigned int old = atomicAdd(cnt, 1u);
    isLast = (old == (unsigned int)(NLB - 1)) ? 1 : 0;
  }
  __syncthreads();
  if (isLast) {
    // All other blocks' atomicAdds are complete (ticket order + fences).
    double q5 = 0.0;
    for (int c = t; c < PRE_BLOCKS; c += 256) q5 += preacc[c];
    q5 = wave_sum_d(q5);
    if (lane == 0) sq[wid] = q5;
    if (t < 40) sacc[t] = atomicAdd(&acc[t], 0.0);   // coherence-point read
    __syncthreads();
    if (t == 0) {
      double Q[5];
#pragma unroll
      for (int j5 = 0; j5 < 5; ++j5) {
        double s = 0.0;
#pragma unroll
        for (int w = 0; w < 8; ++w) s += sacc[j5 * 8 + w];
        Q[j5] = s;
      }
      double bce = Q[0] + sq[0] + sq[1] + sq[2] + sq[3];
      double scs = fmax(Q[1], 1.0);
      double nf = fmax(Q[2], 1.0);
      out[0] = (float)(7.5 * (Q[3] / nf) + 0.5 * (bce / scs) + 1.5 * (Q[4] / nf / 4.0));
    }
  }
}

}  // namespace

extern "C" void kernel_launch(void* const* d_in, const int* in_sizes, int n_in,
                              void* d_out, int out_size, void* d_ws, size_t ws_size,
                              hipStream_t stream) {
  (void)in_sizes; (void)n_in; (void)out_size; (void)ws_size;
  const float* pred_dist = (const float*)d_in[0];
  const float* pred_cls  = (const float*)d_in[1];
  const int*   gt_labels = (const int*)d_in[2];
  const float* gt_bboxes = (const float*)d_in[3];

  // ws layout: [packed u64 B*A][acc 64 d (40 used + cnt @ [48])]
  //            [pbox B*A*4 f][msqrt B*A f][preacc 512 d]
  unsigned long long* packed = (unsigned long long*)d_ws;
  double* acc   = (double*)((char*)d_ws + (size_t)B * A * 8);
  unsigned int* cnt = (unsigned int*)((char*)acc + 48 * 8);
  float*  pbox  = (float*)((char*)acc + 64 * 8);
  float*  msqrt = pbox + (size_t)B * A * 4;
  double* preacc = (double*)(msqrt + (size_t)B * A);
  float*  out   = (float*)d_out;

  hipLaunchKernelGGL(k_pre, dim3(PRE_BLOCKS), dim3(256), 0, stream,
                     pred_dist, pred_cls, pbox, msqrt, packed, preacc, acc, cnt);
  hipLaunchKernelGGL(k_topk, dim3(B * G), dim3(256), 0, stream,
                     pbox, msqrt, gt_bboxes, packed);
  hipLaunchKernelGGL(k_loss, dim3(B * A / 256), dim3(256), 0, stream,
                     pred_dist, pred_cls, gt_labels, gt_bboxes, pbox, packed,
                     acc, preacc, cnt, out);
}

// Round 5
// 238.972 us; speedup vs baseline: 1.0356x; 1.0356x over previous
//
#include <hip/hip_runtime.h>
#include <cmath>

// YOLOv8 loss, B=32, A=8400, G=40, C=80, R=16.
// R10 = best-of-both: the 5-dispatch skeleton (memset/k_pre/k_topk/k_loss/
// k_final — measured 237-240us twice) + this session's pipeline wins:
//   - k_topk: barrier-free wave top-10 + parallel atomicMax publish of
//     packed = (iou_bits<<32 | 63-g)  [proven R4, absmax 0.0]
//   - k_loss: reads best/argmax-g from packed; NO per-anchor gt re-scan.
// The 3-dispatch ticket/fence/last-block variant measured a consistent ~10us
// SLOWER (247.2/247.5 vs 237.4/239.8): the tail-of-k_loss reduction ran on a
// drained GPU behind 1050 serialized fenced tickets. memset+k_final are
// near-free in the capture graph; the fused tail was not.

namespace {

constexpr int B = 32;
constexpr int A = 8400;
constexpr int G = 40;
constexpr int C = 80;
constexpr float EPS = 1e-7f;
constexpr float IMG = 640.0f;

// k_pre tiling (proven R5)
constexpr int TPW = 16;                    // anchors per wave-tile
constexpr int NT = B * A / TPW;            // 16800 tiles (exact)
constexpr int PRE_BLOCKS = 512;
constexpr int NWAVES = PRE_BLOCKS * 4;     // 2048 waves
constexpr int DIST_B = TPW * 64;           // 4096 B dist per tile
constexpr int CLS_B = TPW * 320;           // 5120 B cls per tile
constexpr int SLICE = DIST_B + CLS_B;      // 9216 B per buffer

#define AS1 __attribute__((address_space(1)))
#define AS3 __attribute__((address_space(3)))

// Async global->LDS DMA, 16 B per lane. LDS dest = uniform base + lane*16.
__device__ __forceinline__ void gload_lds16(const void* g, void* l) {
  __builtin_amdgcn_global_load_lds((AS1 void*)(g), (AS3 void*)(l), 16, 0, 0);
}

__device__ __forceinline__ void anchor_of(int a, float& ax, float& ay, float& st) {
  int x, y;
  if (a < 6400)      { x = a % 80; y = a / 80; st = 8.0f; }
  else if (a < 8000) { int t = a - 6400; x = t % 40; y = t / 40; st = 16.0f; }
  else               { int t = a - 8000; x = t % 20; y = t / 20; st = 32.0f; }
  ax = ((float)x + 0.5f) * st;
  ay = ((float)y + 0.5f) * st;
}

// 20 cls logits (this lane's quarter of one anchor): max logit + softplus sum.
// log-batching: sum log1p(e^-|x|) = ln2*(log2(prod1)+log2(prod2)).
__device__ __forceinline__ void cls_part(const float4* c, float& sp, float& mx) {
  float relu = 0.f, p0 = 1.f, p1 = 1.f;
  mx = -3.4e38f;
#pragma unroll
  for (int q = 0; q < 5; ++q) {
    float xs[4] = {c[q].x, c[q].y, c[q].z, c[q].w};
#pragma unroll
    for (int e = 0; e < 4; ++e) {
      float x = xs[e];
      mx = fmaxf(mx, x);
      relu += fmaxf(x, 0.f);
      float ee = __expf(-fabsf(x));
      if (q < 3) p0 *= (1.f + ee); else p1 *= (1.f + ee);
    }
  }
  sp = relu + 0.69314718056f * (__log2f(p0) + __log2f(p1));
}

// softmax-expectation over 16 logits held in 4 float4s.
__device__ __forceinline__ float dist_expect(float4 w0, float4 w1, float4 w2, float4 w3) {
  float x[16] = {w0.x, w0.y, w0.z, w0.w, w1.x, w1.y, w1.z, w1.w,
                 w2.x, w2.y, w2.z, w2.w, w3.x, w3.y, w3.z, w3.w};
  float m = x[0];
#pragma unroll
  for (int e = 1; e < 16; ++e) m = fmaxf(m, x[e]);
  float se = 0.f, sj = 0.f;
#pragma unroll
  for (int e = 0; e < 16; ++e) {
    float ee = __expf(x[e] - m);
    se += ee;
    sj += ee * (float)e;
  }
  return sj / se;
}

// Stage one 16-anchor tile into this wave's LDS buffer (9 async DMA ops).
__device__ __forceinline__ void stage_tile(const char* dbase, const char* cbase,
                                           int tile, char* lbuf, int lane) {
  const char* gd = dbase + (size_t)tile * DIST_B + lane * 16;
  const char* gc = cbase + (size_t)tile * CLS_B + lane * 16;
#pragma unroll
  for (int r = 0; r < 4; ++r) gload_lds16(gd + r * 1024, lbuf + r * 1024);
#pragma unroll
  for (int q = 0; q < 5; ++q) gload_lds16(gc + q * 1024, lbuf + DIST_B + q * 1024);
}

// ---------------------------------------------------------------------------
// k_pre: wave-private DMA double-buffer over 16-anchor tiles.
// Outputs: pbox, msqrt, packed=0, acc[0..7] softplus slots (atomicAdd).
// ---------------------------------------------------------------------------
__global__ __launch_bounds__(256) void k_pre(
    const float* __restrict__ pred_dist, const float* __restrict__ pred_cls,
    float* __restrict__ pbox, float* __restrict__ msqrt,
    unsigned long long* __restrict__ packed, double* __restrict__ acc) {
  __shared__ char smem[4 * 2 * SLICE];   // 73728 B: 4 waves x 2 buffers x 9 KB
  __shared__ double shb[4];
  int t = threadIdx.x, lane = t & 63, wid = t >> 6;
  int j = lane & 3, a16 = lane >> 2;
  char* slice = smem + wid * (2 * SLICE);
  const char* dbase = (const char*)pred_dist;
  const char* cbase = (const char*)pred_cls;

  double spsum = 0.0;
  int cur = blockIdx.x * 4 + wid;
  int buf = 0;
  if (cur < NT) stage_tile(dbase, cbase, cur, slice, lane);

  while (cur < NT) {
    int nxt = cur + NWAVES;
    if (nxt < NT) {
      stage_tile(dbase, cbase, nxt, slice + (buf ^ 1) * SLICE, lane);
      // vmcnt(9): tile `cur`'s 9 DMAs (and older stores) retired; next tile's
      // 9 stay in flight. expcnt/lgkmcnt fields set to no-wait.
      __builtin_amdgcn_s_waitcnt(0xF79);
    } else {
      __builtin_amdgcn_s_waitcnt(0xF70);   // vmcnt(0)
    }

    const char* bp = slice + buf * SLICE;
    // ---- cls: quad layout identical to global layout ----
    float4 c[5];
    const float4* cl = (const float4*)(bp + DIST_B + a16 * 320 + j * 16);
#pragma unroll
    for (int q = 0; q < 5; ++q) c[q] = cl[q * 4];   // byte stride 64
    float sp, mx;
    cls_part(c, sp, mx);
    mx = fmaxf(mx, __shfl_xor(mx, 1));
    mx = fmaxf(mx, __shfl_xor(mx, 2));

    // ---- dist: lane j owns side j of its anchor ----
    const float4* dl = (const float4*)(bp + a16 * 256 + j * 64);
    float de = dist_expect(dl[0], dl[1], dl[2], dl[3]);
    int qb = lane & ~3;
    float e0 = __shfl(de, qb), e1 = __shfl(de, qb + 1);
    float e2 = __shfl(de, qb + 2), e3 = __shfl(de, qb + 3);

    int i = cur * TPW + a16;
    if (j == 0) {
      int a = i % A;
      float ax, ay, st;
      anchor_of(a, ax, ay, st);
      float4 ob;
      ob.x = fminf(fmaxf(ax - e0 * st, 0.f), IMG);
      ob.y = fminf(fmaxf(ay - e1 * st, 0.f), IMG);
      ob.z = fminf(fmaxf(ax + e2 * st, 0.f), IMG);
      ob.w = fminf(fmaxf(ay + e3 * st, 0.f), IMG);
      reinterpret_cast<float4*>(pbox)[i] = ob;
      msqrt[i] = sqrtf(1.f / (1.f + __expf(-mx)));
      packed[i] = 0ull;
    }
    spsum += (double)sp;
    cur = nxt;
    buf ^= 1;
  }

  // ---- block-reduce softplus sum, one atomic per block ----
#pragma unroll
  for (int off = 32; off; off >>= 1) spsum += __shfl_xor(spsum, off);
  if (lane == 0) shb[wid] = spsum;
  __syncthreads();
  if (t == 0) {
    double s = shb[0] + shb[1] + shb[2] + shb[3];
    atomicAdd(&acc[0 * 8 + (blockIdx.x & 7)], s);
  }
}

// ---------------------------------------------------------------------------
// k_topk: one block per (b,g). Per-thread exact top-10 (insert cascade only
// fires for v>0) -> per-wave top-10 via 10 barrier-free butterfly rounds
// (lane k latches round-k winner) -> one __syncthreads -> wave 0 merges the
// 4x10 candidates (anchor indices globally unique -> index-match consume) ->
// lanes 0..9 publish in parallel: atomicMax(packed, iou<<32 | 63-g).
// Max = highest iou; ties -> smallest g (argmax-first semantics).
// ---------------------------------------------------------------------------
__global__ __launch_bounds__(256) void k_topk(
    const float* __restrict__ pbox, const float* __restrict__ msqrt,
    const float* __restrict__ gt_bboxes, unsigned long long* __restrict__ packed) {
  int bg = blockIdx.x;
  int t = threadIdx.x, lane = t & 63, wid = t >> 6;
  int b = bg / G, g = bg % G;
  const float* gp = gt_bboxes + (size_t)bg * 4;
  float gx1 = gp[0], gy1 = gp[1], gx2 = gp[2], gy2 = gp[3];
  float garea = (gx2 - gx1) * (gy2 - gy1);
  const float4* pb = reinterpret_cast<const float4*>(pbox) + (size_t)b * A;
  const float* ms = msqrt + (size_t)b * A;

  float lv[10];
  int li[10];
#pragma unroll
  for (int s = 0; s < 10; ++s) { lv[s] = 0.f; li[s] = 0x7fffffff; }

  for (int a = t; a < A; a += 256) {
    float4 p = pb[a];
    float iw = fmaxf(fminf(gx2, p.z) - fmaxf(gx1, p.x), 0.f);
    float ih = fmaxf(fminf(gy2, p.w) - fmaxf(gy1, p.y), 0.f);
    float inter = iw * ih;
    float parea = (p.z - p.x) * (p.w - p.y);
    float iou = inter / (garea + parea - inter + EPS);
    float i2 = iou * iou;
    float v = ms[a] * i2 * i2 * i2;     // cls^0.5 * iou^6
    if (v > lv[9] || (v == lv[9] && v > 0.f && a < li[9])) {
      float cv = v; int ci = a;
#pragma unroll
      for (int s = 0; s < 10; ++s) {
        bool bt = (cv > lv[s]) || (cv == lv[s] && ci < li[s]);
        float tv = bt ? cv : lv[s]; int ti = bt ? ci : li[s];
        cv = bt ? lv[s] : cv; ci = bt ? li[s] : ci;
        lv[s] = tv; li[s] = ti;
      }
    }
  }

  // ---- per-wave top-10: 10 butterfly-argmax rounds, no barriers ----
  __shared__ float lwv[40];
  __shared__ int lwi[40];
  float kv = 0.f; int ki = 0x7fffffff;   // lane k holds round-k winner
  int ptr = 0;
  for (int k = 0; k < 10; ++k) {
    float hv = lv[0]; int hi = li[0];
#pragma unroll
    for (int s = 1; s < 10; ++s) { bool sel = (ptr == s); hv = sel ? lv[s] : hv; hi = sel ? li[s] : hi; }
    if (ptr > 9) { hv = -1.f; hi = -1; }
    float rv = hv; int ri = hi;
#pragma unroll
    for (int off = 32; off; off >>= 1) {
      float ov = __shfl_xor(rv, off); int oi = __shfl_xor(ri, off);
      if (ov > rv || (ov == rv && oi < ri)) { rv = ov; ri = oi; }
    }
    if (rv <= 0.f) break;    // sorted: all remaining are invalid too
    if (lane == k) { kv = rv; ki = ri; }
    if (hi == ri) ptr++;     // unique anchor index -> exactly one lane advances
  }
  if (lane < 10) { lwv[wid * 10 + lane] = kv; lwi[wid * 10 + lane] = ki; }
  __syncthreads();

  // ---- wave-0 merge of 4 sorted 10-lists + parallel publish ----
  if (wid == 0) {
    float mv = 0.f; int mi = 0x7fffffff;
    if (lane < 40) { mv = lwv[lane]; mi = lwi[lane]; }
    int outi = -1;
    for (int k = 0; k < 10; ++k) {
      float rv = mv; int ri = mi;
#pragma unroll
      for (int off = 32; off; off >>= 1) {
        float ov = __shfl_xor(rv, off); int oi = __shfl_xor(ri, off);
        if (ov > rv || (ov == rv && oi < ri)) { rv = ov; ri = oi; }
      }
      if (rv <= 0.f) break;
      if (lane == k) outi = ri;          // lane k owns winner k
      if (mi == ri) { mv = 0.f; mi = 0x7fffffff; }  // consume (index unique)
    }
    if (outi >= 0) {
      // Winner valid (v>0 => iou>0). Recompute its iou (identical expression
      // as the scan -> identical value) and publish.
      float4 p = pb[outi];
      float iw = fmaxf(fminf(gx2, p.z) - fmaxf(gx1, p.x), 0.f);
      float ih = fmaxf(fminf(gy2, p.w) - fmaxf(gy1, p.y), 0.f);
      float inter = iw * ih;
      float parea = (p.z - p.x) * (p.w - p.y);
      float iou = inter / (garea + parea - inter + EPS);
      unsigned long long pk =
          ((unsigned long long)__float_as_uint(iou) << 32) | (unsigned int)(63 - g);
      atomicMax(&packed[(size_t)b * A + outi], pk);
    }
  }
}

__device__ __forceinline__ float ciou_f(float4 p, float t0, float t1, float t2, float t3) {
  float iw = fmaxf(fminf(p.z, t2) - fmaxf(p.x, t0), 0.f);
  float ih = fmaxf(fminf(p.w, t3) - fmaxf(p.y, t1), 0.f);
  float inter = iw * ih;
  float w1 = fmaxf(p.z - p.x, EPS), h1 = fmaxf(p.w - p.y, EPS);
  float w2 = fmaxf(t2 - t0, EPS), h2 = fmaxf(t3 - t1, EPS);
  float uni = w1 * h1 + w2 * h2 - inter + EPS;
  float iou = inter / uni;
  float cw = fmaxf(p.z, t2) - fminf(p.x, t0);
  float ch = fmaxf(p.w, t3) - fminf(p.y, t1);
  float c2 = cw * cw + ch * ch + EPS;
  float dx = (p.x + p.z) * 0.5f - (t0 + t2) * 0.5f;
  float dy = (p.y + p.w) * 0.5f - (t1 + t3) * 0.5f;
  float rho2 = dx * dx + dy * dy;
  float dat = atanf(w2 / h2) - atanf(w1 / h1);
  const float c4pi2 = (float)(4.0 / (M_PI * M_PI));
  float v = c4pi2 * dat * dat;
  float alpha = v / (1.0f - iou + v + EPS);
  float r = iou - (rho2 / c2 + v * alpha);
  return fminf(fmaxf(r, -1.f), 1.f);
}

__device__ __forceinline__ float wave_sum(float v) {
#pragma unroll
  for (int off = 32; off; off >>= 1) v += __shfl_xor(v, off);
  return v;
}

// ---------------------------------------------------------------------------
// k_loss: packed-driven (best iou + argmax-g read directly; no gt re-scan).
// acc slots: [0]=bce(+softplus), [1]=score_sum, [2]=num_fg, [3]=box, [4]=dfl.
// Grid = B*A/256.
// ---------------------------------------------------------------------------
__global__ __launch_bounds__(256) void k_loss(
    const float* __restrict__ pred_dist, const float* __restrict__ pred_cls,
    const int* __restrict__ gt_labels, const float* __restrict__ gt_bboxes,
    const float* __restrict__ pbox, const unsigned long long* __restrict__ packed,
    double* __restrict__ acc) {
  int t = threadIdx.x, lane = t & 63, wid = t >> 6;
  int i = blockIdx.x * 256 + t;
  int b = i / A, a = i - b * A;
  unsigned long long pk = packed[i];
  float corr = 0.f, sc = 0.f, nfg = 0.f, box = 0.f, dfl = 0.f;
  if (pk) {
    int bestg = 63 - (int)(pk & 63ull);
    float best = __uint_as_float((unsigned int)(pk >> 32));
    float4 p = reinterpret_cast<const float4*>(pbox)[i];
    sc = best;
    nfg = 1.f;
    int lab = gt_labels[b * G + bestg];
    lab = lab < 0 ? 0 : (lab > C - 1 ? C - 1 : lab);
    float xl = pred_cls[(size_t)i * C + lab];
    corr = -xl * best;                 // the -x*t BCE term
    const float* gp = gt_bboxes + (size_t)(b * G + bestg) * 4;
    float t0 = gp[0], t1 = gp[1], t2 = gp[2], t3 = gp[3];
    box = 1.0f - ciou_f(p, t0, t1, t2, t3);
    float ax, ay, st;
    anchor_of(a, ax, ay, st);
    float rst = 1.f / st;
    float tgt[4] = {(ax - t0) * rst, (ay - t1) * rst, (t2 - ax) * rst, (t3 - ay) * rst};
    const float4* dr = reinterpret_cast<const float4*>(pred_dist) + (size_t)i * 16;
    const float* drf = pred_dist + (size_t)i * 64;
#pragma unroll
    for (int l = 0; l < 4; ++l) {
      float4 u0 = dr[4 * l], u1 = dr[4 * l + 1], u2 = dr[4 * l + 2], u3 = dr[4 * l + 3];
      float xs[16] = {u0.x, u0.y, u0.z, u0.w, u1.x, u1.y, u1.z, u1.w,
                      u2.x, u2.y, u2.z, u2.w, u3.x, u3.y, u3.z, u3.w};
      float m = xs[0];
#pragma unroll
      for (int e = 1; e < 16; ++e) m = fmaxf(m, xs[e]);
      float se = 0.f;
#pragma unroll
      for (int e = 0; e < 16; ++e) se += __expf(xs[e] - m);
      float lse = m + __logf(se);
      float tt = fminf(fmaxf(tgt[l], 0.f), 14.99f);
      int tl = (int)tt;                 // tt >= 0 so trunc == floor
      float wr = tt - (float)tl;
      float wl = 1.f - wr;
      float xa = drf[l * 16 + tl];      // L1-hot re-read, avoids scratch array
      float xb = drf[l * 16 + tl + 1];
      dfl += (lse - xa) * wl + (lse - xb) * wr;
    }
  }
  float s0 = wave_sum(corr), s1 = wave_sum(sc), s2 = wave_sum(nfg);
  float s3 = wave_sum(box), s4 = wave_sum(dfl);
  __shared__ float sh[4][5];
  if (lane == 0) { sh[wid][0] = s0; sh[wid][1] = s1; sh[wid][2] = s2; sh[wid][3] = s3; sh[wid][4] = s4; }
  __syncthreads();
  if (t == 0) {
    double a0 = 0, a1 = 0, a2 = 0, a3 = 0, a4 = 0;
#pragma unroll
    for (int w = 0; w < 4; ++w) {
      a0 += sh[w][0]; a1 += sh[w][1]; a2 += sh[w][2]; a3 += sh[w][3]; a4 += sh[w][4];
    }
    if (a2 != 0.0) {
      int slot = blockIdx.x & 7;
      atomicAdd(&acc[0 * 8 + slot], a0);
      atomicAdd(&acc[1 * 8 + slot], a1);
      atomicAdd(&acc[2 * 8 + slot], a2);
      atomicAdd(&acc[3 * 8 + slot], a3);
      atomicAdd(&acc[4 * 8 + slot], a4);
    }
  }
}

__global__ void k_final(const double* __restrict__ acc, float* __restrict__ out) {
  double q[5];
#pragma unroll
  for (int jj = 0; jj < 5; ++jj) {
    double s = 0;
#pragma unroll
    for (int w = 0; w < 8; ++w) s += acc[jj * 8 + w];
    q[jj] = s;
  }
  double bce = q[0];
  double scs = fmax(q[1], 1.0);
  double nf = fmax(q[2], 1.0);
  double loss = 7.5 * (q[3] / nf) + 0.5 * (bce / scs) + 1.5 * (q[4] / nf / 4.0);
  out[0] = (float)loss;
}

}  // namespace

extern "C" void kernel_launch(void* const* d_in, const int* in_sizes, int n_in,
                              void* d_out, int out_size, void* d_ws, size_t ws_size,
                              hipStream_t stream) {
  (void)in_sizes; (void)n_in; (void)out_size; (void)ws_size;
  const float* pred_dist = (const float*)d_in[0];
  const float* pred_cls  = (const float*)d_in[1];
  const int*   gt_labels = (const int*)d_in[2];
  const float* gt_bboxes = (const float*)d_in[3];

  // ws layout: [packed u64 B*A][acc 64 doubles][pbox B*A*4 f][msqrt B*A f]
  unsigned long long* packed = (unsigned long long*)d_ws;
  double* acc  = (double*)((char*)d_ws + (size_t)B * A * 8);
  float*  pbox = (float*)((char*)d_ws + (size_t)B * A * 8 + 64 * 8);
  float*  msqrt = pbox + (size_t)B * A * 4;
  float*  out = (float*)d_out;

  hipMemsetAsync(acc, 0, 64 * 8, stream);   // only the accumulators
  hipLaunchKernelGGL(k_pre, dim3(PRE_BLOCKS), dim3(256), 0, stream,
                     pred_dist, pred_cls, pbox, msqrt, packed, acc);
  hipLaunchKernelGGL(k_topk, dim3(B * G), dim3(256), 0, stream,
                     pbox, msqrt, gt_bboxes, packed);
  hipLaunchKernelGGL(k_loss, dim3(B * A / 256), dim3(256), 0, stream,
                     pred_dist, pred_cls, gt_labels, gt_bboxes, pbox, packed, acc);
  hipLaunchKernelGGL(k_final, dim3(1), dim3(1), 0, stream, acc, out);
}